// Round 1
// baseline (609.529 us; speedup 1.0000x reference)
//
#include <hip/hip_runtime.h>

// Perspective3d: voxels [4,32,64,64,64] f32, rot [4,4,4], tran [4,3], s [4,3],
// det [4,2], xy_sample=96, z_sample=48. Output [4,32,48,96,96] f32.

static constexpr int Bn = 4, Cn = 32, DV = 64, HV = 64, WV = 64;
static constexpr int ZS = 48, XY = 96;
static constexpr int SP = ZS * XY * XY;      // 442368 spatial locations / batch
static constexpr int VOXCH = DV * HV * WV;   // 262144 elements / channel

__global__ __launch_bounds__(256) void persp3d_kernel(
    const float* __restrict__ vox,
    const float* __restrict__ rot,
    const float* __restrict__ tran,
    const float* __restrict__ sc,
    const float* __restrict__ det,
    float* __restrict__ out)
{
    const int tid = blockIdx.x * 256 + threadIdx.x;
    const int b  = tid / SP;
    const int sp = tid - b * SP;
    const int z  = sp / (XY * XY);
    const int r  = sp - z * (XY * XY);
    const int h  = r / XY;
    const int w  = r - h * XY;

    const float* R  = rot  + b * 16;
    const float* T  = tran + b * 3;
    const float* S  = sc   + b * 3;
    const float* DT = det  + b * 2;

    const float t0 = T[0], t1 = T[1], t2 = T[2];

    // M[i][k] = (1/s_i) * R[k][i] (k<3);  M[i][3] = -(1/s_i) * sum_j R[j][i] t_j
    float M[3][4];
#pragma unroll
    for (int i = 0; i < 3; ++i) {
        const float inv = 1.0f / S[i];
        const float m0 = R[0 * 4 + i], m1 = R[1 * 4 + i], m2 = R[2 * 4 + i];
        M[i][0] = inv * m0;
        M[i][1] = inv * m1;
        M[i][2] = inv * m2;
        M[i][3] = -inv * (m0 * t0 + m1 * t1 + m2 * t2);
    }

    // camera-frame ray grid. linspace(0,96,96): step 96/95 (endpoint incl).
    // linspace(-0.5,0.5,48): step 1/47.
    const float STEP = 96.0f / 95.0f;
    const float Zt = -0.5f + z * (1.0f / 47.0f) + t2;
    const float Xt = (w * STEP - 48.0f + DT[0]) * Zt * 0.01f;  // /FX=100
    const float Yt = (h * STEP - 48.0f + DT[1]) * Zt * 0.01f;  // /FY=100

    // world coords; homogeneous w-component is exactly 1 (bottom row [0,0,0,1])
    const float gx = 2.0f * (M[0][0] * Xt + M[0][1] * Yt + M[0][2] * Zt + M[0][3]);
    const float gy = 2.0f * (M[1][0] * Xt + M[1][1] * Yt + M[1][2] * Zt + M[1][3]);
    const float gz = 2.0f * (M[2][0] * Xt + M[2][1] * Yt + M[2][2] * Zt + M[2][3]);

    // grid_sample coords, align_corners=True
    const float ix = (gx + 1.0f) * 0.5f * (WV - 1);
    const float iy = (gy + 1.0f) * 0.5f * (HV - 1);
    const float iz = (gz + 1.0f) * 0.5f * (DV - 1);

    const float fx0 = floorf(ix), fy0 = floorf(iy), fz0 = floorf(iz);
    const float fx = ix - fx0, fy = iy - fy0, fz = iz - fz0;
    const int x0 = (int)fx0, y0 = (int)fy0, z0 = (int)fz0;
    const int x1 = x0 + 1, y1 = y0 + 1, z1 = z0 + 1;

    // fold per-axis validity (zeros padding) into lerp weights
    const float ax0 = (1.0f - fx) * ((x0 >= 0 && x0 < WV) ? 1.0f : 0.0f);
    const float ax1 = fx          * ((x1 >= 0 && x1 < WV) ? 1.0f : 0.0f);
    const float ay0 = (1.0f - fy) * ((y0 >= 0 && y0 < HV) ? 1.0f : 0.0f);
    const float ay1 = fy          * ((y1 >= 0 && y1 < HV) ? 1.0f : 0.0f);
    const float az0 = (1.0f - fz) * ((z0 >= 0 && z0 < DV) ? 1.0f : 0.0f);
    const float az1 = fz          * ((z1 >= 0 && z1 < DV) ? 1.0f : 0.0f);

    const int xc0 = min(max(x0, 0), WV - 1), xc1 = min(max(x1, 0), WV - 1);
    const int yc0 = min(max(y0, 0), HV - 1), yc1 = min(max(y1, 0), HV - 1);
    const int zc0 = min(max(z0, 0), DV - 1), zc1 = min(max(z1, 0), DV - 1);

    const int o000 = (zc0 * HV + yc0) * WV + xc0;
    const int o001 = (zc0 * HV + yc0) * WV + xc1;
    const int o010 = (zc0 * HV + yc1) * WV + xc0;
    const int o011 = (zc0 * HV + yc1) * WV + xc1;
    const int o100 = (zc1 * HV + yc0) * WV + xc0;
    const int o101 = (zc1 * HV + yc0) * WV + xc1;
    const int o110 = (zc1 * HV + yc1) * WV + xc0;
    const int o111 = (zc1 * HV + yc1) * WV + xc1;

    const float* p = vox + (size_t)b * Cn * VOXCH;
    float* op = out + (size_t)b * Cn * SP + sp;

#pragma unroll 4
    for (int c = 0; c < Cn; ++c) {
        const float v000 = p[o000], v001 = p[o001];
        const float v010 = p[o010], v011 = p[o011];
        const float v100 = p[o100], v101 = p[o101];
        const float v110 = p[o110], v111 = p[o111];
        const float q00 = ax0 * v000 + ax1 * v001;   // z0,y0
        const float q01 = ax0 * v010 + ax1 * v011;   // z0,y1
        const float q10 = ax0 * v100 + ax1 * v101;   // z1,y0
        const float q11 = ax0 * v110 + ax1 * v111;   // z1,y1
        const float r0 = ay0 * q00 + ay1 * q01;
        const float r1 = ay0 * q10 + ay1 * q11;
        *op = az0 * r0 + az1 * r1;
        p  += VOXCH;
        op += SP;
    }
}

extern "C" void kernel_launch(void* const* d_in, const int* in_sizes, int n_in,
                              void* d_out, int out_size, void* d_ws, size_t ws_size,
                              hipStream_t stream) {
    const float* vox  = (const float*)d_in[0];
    const float* rot  = (const float*)d_in[1];
    const float* tran = (const float*)d_in[2];
    const float* sc   = (const float*)d_in[3];
    const float* det  = (const float*)d_in[4];
    float* out = (float*)d_out;

    const int total = Bn * SP;              // 1,769,472 (divisible by 256)
    persp3d_kernel<<<dim3(total / 256), dim3(256), 0, stream>>>(
        vox, rot, tran, sc, det, out);
}

// Round 2
// 550.814 us; speedup vs baseline: 1.1066x; 1.1066x over previous
//
#include <hip/hip_runtime.h>

// Perspective3d: voxels [4,32,64,64,64] f32, rot [4,4,4], tran [4,3], s [4,3],
// det [4,2], xy_sample=96, z_sample=48. Output [4,32,48,96,96] f32.
//
// Round 2: gather-latency-bound fix. 3D-tiled blocks (32w x 4h x 2z) +
// bijective XCD-chunk swizzle so each XCD's L2 holds a contiguous z-slab
// (per-channel slab footprint ~0.5 MiB << 4 MiB L2). Non-temporal output
// stores keep the 226 MB stream from evicting voxel lines.

static constexpr int Bn = 4, Cn = 32, DV = 64, HV = 64, WV = 64;
static constexpr int ZS = 48, XY = 96;
static constexpr int SP = ZS * XY * XY;      // 442368 spatial / batch
static constexpr int VOXCH = DV * HV * WV;   // 262144 elements / channel

static constexpr int TW = 32, TH = 4, TZ = 2;            // block tile
static constexpr int NBW = XY / TW, NBH = XY / TH, NBZ = ZS / TZ;  // 3,24,24
static constexpr int BLOCKS_PER_B = NBW * NBH * NBZ;     // 1728
static constexpr int NBLOCKS = Bn * BLOCKS_PER_B;        // 6912 (div by 8)
static constexpr int NXCD = 8;
static constexpr int CHUNK = NBLOCKS / NXCD;             // 864

__global__ __launch_bounds__(256) void persp3d_kernel(
    const float* __restrict__ vox,
    const float* __restrict__ rot,
    const float* __restrict__ tran,
    const float* __restrict__ sc,
    const float* __restrict__ det,
    float* __restrict__ out)
{
    // ---- XCD-aware swizzle: hardware assigns blockIdx round-robin to XCDs;
    // remap so each XCD sweeps a contiguous chunk (z-slab of one batch).
    const int xcd = blockIdx.x % NXCD;
    const int logical = xcd * CHUNK + blockIdx.x / NXCD;

    const int b   = logical / BLOCKS_PER_B;
    int rem       = logical - b * BLOCKS_PER_B;
    const int bz  = rem / (NBH * NBW);
    rem          -= bz * (NBH * NBW);
    const int bh  = rem / NBW;
    const int bw  = rem - bh * NBW;

    const int t  = threadIdx.x;
    const int tw = t & (TW - 1);
    const int th = (t >> 5) & (TH - 1);
    const int tz = t >> 7;

    const int w = bw * TW + tw;
    const int h = bh * TH + th;
    const int z = bz * TZ + tz;
    const int sp = (z * XY + h) * XY + w;

    const float* R  = rot  + b * 16;
    const float* T  = tran + b * 3;
    const float* S  = sc   + b * 3;
    const float* DT = det  + b * 2;

    const float t0 = T[0], t1 = T[1], t2 = T[2];

    // M[i][k] = (1/s_i) * R[k][i] (k<3);  M[i][3] = -(1/s_i) * sum_j R[j][i] t_j
    float M[3][4];
#pragma unroll
    for (int i = 0; i < 3; ++i) {
        const float inv = 1.0f / S[i];
        const float m0 = R[0 * 4 + i], m1 = R[1 * 4 + i], m2 = R[2 * 4 + i];
        M[i][0] = inv * m0;
        M[i][1] = inv * m1;
        M[i][2] = inv * m2;
        M[i][3] = -inv * (m0 * t0 + m1 * t1 + m2 * t2);
    }

    // camera-frame ray grid. linspace(0,96,96): step 96/95 (endpoint incl).
    // linspace(-0.5,0.5,48): step 1/47.
    const float STEP = 96.0f / 95.0f;
    const float Zt = -0.5f + z * (1.0f / 47.0f) + t2;
    const float Xt = (w * STEP - 48.0f + DT[0]) * Zt * 0.01f;  // /FX=100
    const float Yt = (h * STEP - 48.0f + DT[1]) * Zt * 0.01f;  // /FY=100

    // world coords; homogeneous w is exactly 1 (bottom row [0,0,0,1])
    const float gx = 2.0f * (M[0][0] * Xt + M[0][1] * Yt + M[0][2] * Zt + M[0][3]);
    const float gy = 2.0f * (M[1][0] * Xt + M[1][1] * Yt + M[1][2] * Zt + M[1][3]);
    const float gz = 2.0f * (M[2][0] * Xt + M[2][1] * Yt + M[2][2] * Zt + M[2][3]);

    // grid_sample coords, align_corners=True
    const float ix = (gx + 1.0f) * 0.5f * (WV - 1);
    const float iy = (gy + 1.0f) * 0.5f * (HV - 1);
    const float iz = (gz + 1.0f) * 0.5f * (DV - 1);

    const float fx0 = floorf(ix), fy0 = floorf(iy), fz0 = floorf(iz);
    const float fx = ix - fx0, fy = iy - fy0, fz = iz - fz0;
    const int x0 = (int)fx0, y0 = (int)fy0, z0 = (int)fz0;
    const int x1 = x0 + 1, y1 = y0 + 1, z1 = z0 + 1;

    // fold per-axis validity (zeros padding) into lerp weights
    const float ax0 = (1.0f - fx) * ((x0 >= 0 && x0 < WV) ? 1.0f : 0.0f);
    const float ax1 = fx          * ((x1 >= 0 && x1 < WV) ? 1.0f : 0.0f);
    const float ay0 = (1.0f - fy) * ((y0 >= 0 && y0 < HV) ? 1.0f : 0.0f);
    const float ay1 = fy          * ((y1 >= 0 && y1 < HV) ? 1.0f : 0.0f);
    const float az0 = (1.0f - fz) * ((z0 >= 0 && z0 < DV) ? 1.0f : 0.0f);
    const float az1 = fz          * ((z1 >= 0 && z1 < DV) ? 1.0f : 0.0f);

    const int xc0 = min(max(x0, 0), WV - 1), xc1 = min(max(x1, 0), WV - 1);
    const int yc0 = min(max(y0, 0), HV - 1), yc1 = min(max(y1, 0), HV - 1);
    const int zc0 = min(max(z0, 0), DV - 1), zc1 = min(max(z1, 0), DV - 1);

    const int o000 = (zc0 * HV + yc0) * WV + xc0;
    const int o001 = (zc0 * HV + yc0) * WV + xc1;
    const int o010 = (zc0 * HV + yc1) * WV + xc0;
    const int o011 = (zc0 * HV + yc1) * WV + xc1;
    const int o100 = (zc1 * HV + yc0) * WV + xc0;
    const int o101 = (zc1 * HV + yc0) * WV + xc1;
    const int o110 = (zc1 * HV + yc1) * WV + xc0;
    const int o111 = (zc1 * HV + yc1) * WV + xc1;

    const float* p = vox + (size_t)b * Cn * VOXCH;
    float* op = out + (size_t)b * Cn * SP + sp;

#pragma unroll 8
    for (int c = 0; c < Cn; ++c) {
        const float v000 = p[o000], v001 = p[o001];
        const float v010 = p[o010], v011 = p[o011];
        const float v100 = p[o100], v101 = p[o101];
        const float v110 = p[o110], v111 = p[o111];
        const float q00 = ax0 * v000 + ax1 * v001;   // z0,y0
        const float q01 = ax0 * v010 + ax1 * v011;   // z0,y1
        const float q10 = ax0 * v100 + ax1 * v101;   // z1,y0
        const float q11 = ax0 * v110 + ax1 * v111;   // z1,y1
        const float r0 = ay0 * q00 + ay1 * q01;
        const float r1 = ay0 * q10 + ay1 * q11;
        __builtin_nontemporal_store(az0 * r0 + az1 * r1, op);
        p  += VOXCH;
        op += SP;
    }
}

extern "C" void kernel_launch(void* const* d_in, const int* in_sizes, int n_in,
                              void* d_out, int out_size, void* d_ws, size_t ws_size,
                              hipStream_t stream) {
    const float* vox  = (const float*)d_in[0];
    const float* rot  = (const float*)d_in[1];
    const float* tran = (const float*)d_in[2];
    const float* sc   = (const float*)d_in[3];
    const float* det  = (const float*)d_in[4];
    float* out = (float*)d_out;

    persp3d_kernel<<<dim3(NBLOCKS), dim3(256), 0, stream>>>(
        vox, rot, tran, sc, det, out);
}

// Round 3
// 200.943 us; speedup vs baseline: 3.0334x; 2.7412x over previous
//
#include <hip/hip_runtime.h>

// Perspective3d: voxels [4,32,64,64,64] f32 -> out [4,32,48,96,96] f32.
//
// Round 3: kill TA address-divergence. Pre-pass transposes voxels to
// [B,D,H,W,C] (channels-last, 128B per voxel) in d_ws. Main kernel maps
// lanes->channels: each half-wave (32 lanes) loads one corner's 32 channels
// as one contiguous 128B segment (4 lines per wave64 gather vs ~40 before).
// Per-wave LDS 32x32 tile transposes results back so output stores stay
// coalesced in the [C,Z,H,W] layout.

static constexpr int Bn = 4, Cn = 32, DV = 64, HV = 64, WV = 64;
static constexpr int ZS = 48, XY = 96;
static constexpr int SP = ZS * XY * XY;            // 442368 spatial / batch
static constexpr long long VOXCH = (long long)DV * HV * WV;  // 262144
static constexpr size_t WS_NEED = (size_t)Bn * VOXCH * Cn * 4;  // 134.2 MB

// ---------------- pre-pass: [B,C,DHW] -> [B,DHW,C] ----------------
__global__ __launch_bounds__(256) void transpose_cl(
    const float* __restrict__ vox, float* __restrict__ voxt)
{
    __shared__ float tile[32][65];
    const int nt = (int)(VOXCH / 64);          // 4096 tiles per batch
    const int blk = blockIdx.x;
    const int b  = blk / nt;
    const int v0 = (blk - b * nt) * 64;
    const int t  = threadIdx.x;
    {
        const int c = t >> 3;                  // 0..31
        const int i = (t & 7) * 8;             // 0..56
        const float* src = vox + ((size_t)(b * Cn + c)) * VOXCH + v0 + i;
        const float4 a0 = *(const float4*)src;
        const float4 a1 = *(const float4*)(src + 4);
        tile[c][i + 0] = a0.x; tile[c][i + 1] = a0.y;
        tile[c][i + 2] = a0.z; tile[c][i + 3] = a0.w;
        tile[c][i + 4] = a1.x; tile[c][i + 5] = a1.y;
        tile[c][i + 6] = a1.z; tile[c][i + 7] = a1.w;
    }
    __syncthreads();
    {
        const int v = t >> 2;                  // 0..63
        const int c = (t & 3) * 8;             // 0,8,16,24
        float4 o0, o1;
        o0.x = tile[c + 0][v]; o0.y = tile[c + 1][v];
        o0.z = tile[c + 2][v]; o0.w = tile[c + 3][v];
        o1.x = tile[c + 4][v]; o1.y = tile[c + 5][v];
        o1.z = tile[c + 6][v]; o1.w = tile[c + 7][v];
        float* dst = voxt + ((size_t)b * VOXCH + v0 + v) * Cn + c;
        *(float4*)dst = o0;
        *((float4*)(dst + 4)) = o1;
    }
}

// ---------------- main: lanes = channels, coalesced corner gathers --------
static constexpr int NBLK2 = Bn * ZS * XY;     // 18432 blocks (one (b,z,h) row)
static constexpr int CH2   = NBLK2 / 8;        // 2304 per XCD

__global__ __launch_bounds__(192) void sample_cl(
    const float* __restrict__ voxt,
    const float* __restrict__ rot,
    const float* __restrict__ tran,
    const float* __restrict__ sc,
    const float* __restrict__ det,
    float* __restrict__ out)
{
    __shared__ float tr[3][32][33];
    // bijective XCD-chunk swizzle (18432 % 8 == 0)
    const int logical = (blockIdx.x % 8) * CH2 + blockIdx.x / 8;
    const int b   = logical / (ZS * XY);
    const int rem = logical - b * (ZS * XY);
    const int z   = rem / XY;
    const int h   = rem - z * XY;

    const int wave = threadIdx.x >> 6;         // 0..2 -> w-tile of 32
    const int lane = threadIdx.x & 63;
    const int p    = lane >> 5;                // sample parity within pair
    const int c    = lane & 31;                // channel owned by this lane
    const int w0   = wave * 32;

    const float* R  = rot  + b * 16;
    const float* T  = tran + b * 3;
    const float* S  = sc   + b * 3;
    const float* DT = det  + b * 2;
    const float t0 = T[0], t1 = T[1], t2 = T[2];

    float M[3][4];
#pragma unroll
    for (int i2 = 0; i2 < 3; ++i2) {
        const float inv = 1.0f / S[i2];
        const float m0 = R[0 * 4 + i2], m1 = R[1 * 4 + i2], m2 = R[2 * 4 + i2];
        M[i2][0] = inv * m0;
        M[i2][1] = inv * m1;
        M[i2][2] = inv * m2;
        M[i2][3] = -inv * (m0 * t0 + m1 * t1 + m2 * t2);
    }

    const float STEP = 96.0f / 95.0f;
    const float Zt  = -0.5f + z * (1.0f / 47.0f) + t2;
    const float Yt  = (h * STEP - 48.0f + DT[1]) * Zt * 0.01f;
    const float Xts = STEP * Zt * 0.01f;              // dXt/dw
    const float Xt0 = (-48.0f + DT[0]) * Zt * 0.01f;  // Xt at w=0

    // voxel-index coords are affine in w: i*(w) = i*0 + w * i*s
    const float gx0 = 2.0f * (M[0][0] * Xt0 + M[0][1] * Yt + M[0][2] * Zt + M[0][3]);
    const float gy0 = 2.0f * (M[1][0] * Xt0 + M[1][1] * Yt + M[1][2] * Zt + M[1][3]);
    const float gz0 = 2.0f * (M[2][0] * Xt0 + M[2][1] * Yt + M[2][2] * Zt + M[2][3]);
    const float ix0 = (gx0 + 1.0f) * 31.5f, ixs = 63.0f * M[0][0] * Xts;
    const float iy0 = (gy0 + 1.0f) * 31.5f, iys = 63.0f * M[1][0] * Xts;
    const float iz0 = (gz0 + 1.0f) * 31.5f, izs = 63.0f * M[2][0] * Xts;

    const float* vb = voxt + (size_t)b * VOXCH * Cn;
    const float fw0 = (float)w0;

#pragma unroll 4
    for (int i = 0; i < 16; ++i) {
        const float fw = fw0 + (float)(2 * i + p);
        const float ix = ix0 + fw * ixs;
        const float iy = iy0 + fw * iys;
        const float iz = iz0 + fw * izs;

        const float fxf = floorf(ix), fyf = floorf(iy), fzf = floorf(iz);
        const float fx = ix - fxf, fy = iy - fyf, fz = iz - fzf;
        const int x0 = (int)fxf, y0 = (int)fyf, z0 = (int)fzf;

        const float ax0 = (1.0f - fx) * ((x0 >= 0     && x0 < WV)     ? 1.0f : 0.0f);
        const float ax1 = fx          * ((x0 + 1 >= 0 && x0 + 1 < WV) ? 1.0f : 0.0f);
        const float ay0 = (1.0f - fy) * ((y0 >= 0     && y0 < HV)     ? 1.0f : 0.0f);
        const float ay1 = fy          * ((y0 + 1 >= 0 && y0 + 1 < HV) ? 1.0f : 0.0f);
        const float az0 = (1.0f - fz) * ((z0 >= 0     && z0 < DV)     ? 1.0f : 0.0f);
        const float az1 = fz          * ((z0 + 1 >= 0 && z0 + 1 < DV) ? 1.0f : 0.0f);

        const int xc0 = min(max(x0, 0), WV - 1), xc1 = min(max(x0 + 1, 0), WV - 1);
        const int yc0 = min(max(y0, 0), HV - 1), yc1 = min(max(y0 + 1, 0), HV - 1);
        const int zc0 = min(max(z0, 0), DV - 1), zc1 = min(max(z0 + 1, 0), DV - 1);

        // channels-last offsets; half-wave (32 lanes) -> one 128B segment
        const int o000 = (((zc0 * HV + yc0) * WV) + xc0) * Cn + c;
        const int o001 = (((zc0 * HV + yc0) * WV) + xc1) * Cn + c;
        const int o010 = (((zc0 * HV + yc1) * WV) + xc0) * Cn + c;
        const int o011 = (((zc0 * HV + yc1) * WV) + xc1) * Cn + c;
        const int o100 = (((zc1 * HV + yc0) * WV) + xc0) * Cn + c;
        const int o101 = (((zc1 * HV + yc0) * WV) + xc1) * Cn + c;
        const int o110 = (((zc1 * HV + yc1) * WV) + xc0) * Cn + c;
        const int o111 = (((zc1 * HV + yc1) * WV) + xc1) * Cn + c;

        const float v000 = vb[o000], v001 = vb[o001];
        const float v010 = vb[o010], v011 = vb[o011];
        const float v100 = vb[o100], v101 = vb[o101];
        const float v110 = vb[o110], v111 = vb[o111];

        const float q00 = ax0 * v000 + ax1 * v001;
        const float q01 = ax0 * v010 + ax1 * v011;
        const float q10 = ax0 * v100 + ax1 * v101;
        const float q11 = ax0 * v110 + ax1 * v111;
        const float r0  = ay0 * q00 + ay1 * q01;
        const float r1  = ay0 * q10 + ay1 * q11;

        tr[wave][2 * i + p][c] = az0 * r0 + az1 * r1;
    }

    __syncthreads();

    // store phase: lanes -> consecutive w, coalesced 128B rows per channel
    const size_t obase = (size_t)b * Cn * SP + (size_t)(z * XY + h) * XY + w0;
    const int wl = lane & 31;
#pragma unroll
    for (int c2 = 0; c2 < 16; ++c2) {
        const int cc = 2 * c2 + p;
        __builtin_nontemporal_store(tr[wave][wl][cc],
                                    out + obase + (size_t)cc * SP + wl);
    }
}

// ---------------- fallback (round-2 kernel) if ws too small ----------------
static constexpr int TW = 32, TH = 4, TZ = 2;
static constexpr int NBW = XY / TW, NBH = XY / TH, NBZ = ZS / TZ;
static constexpr int BLOCKS_PER_B = NBW * NBH * NBZ;
static constexpr int NBLOCKS = Bn * BLOCKS_PER_B;
static constexpr int CHUNK = NBLOCKS / 8;

__global__ __launch_bounds__(256) void persp3d_fallback(
    const float* __restrict__ vox, const float* __restrict__ rot,
    const float* __restrict__ tran, const float* __restrict__ sc,
    const float* __restrict__ det, float* __restrict__ out)
{
    const int xcd = blockIdx.x % 8;
    const int logical = xcd * CHUNK + blockIdx.x / 8;
    const int b = logical / BLOCKS_PER_B;
    int rem = logical - b * BLOCKS_PER_B;
    const int bz = rem / (NBH * NBW);
    rem -= bz * (NBH * NBW);
    const int bh = rem / NBW;
    const int bw = rem - bh * NBW;
    const int t = threadIdx.x;
    const int w = bw * TW + (t & (TW - 1));
    const int h = bh * TH + ((t >> 5) & (TH - 1));
    const int z = bz * TZ + (t >> 7);
    const int sp = (z * XY + h) * XY + w;

    const float* R = rot + b * 16;
    const float* T = tran + b * 3;
    const float* S = sc + b * 3;
    const float* DT = det + b * 2;
    const float t0 = T[0], t1 = T[1], t2 = T[2];
    float M[3][4];
#pragma unroll
    for (int i = 0; i < 3; ++i) {
        const float inv = 1.0f / S[i];
        const float m0 = R[0 * 4 + i], m1 = R[1 * 4 + i], m2 = R[2 * 4 + i];
        M[i][0] = inv * m0; M[i][1] = inv * m1; M[i][2] = inv * m2;
        M[i][3] = -inv * (m0 * t0 + m1 * t1 + m2 * t2);
    }
    const float STEP = 96.0f / 95.0f;
    const float Zt = -0.5f + z * (1.0f / 47.0f) + t2;
    const float Xt = (w * STEP - 48.0f + DT[0]) * Zt * 0.01f;
    const float Yt = (h * STEP - 48.0f + DT[1]) * Zt * 0.01f;
    const float gx = 2.0f * (M[0][0] * Xt + M[0][1] * Yt + M[0][2] * Zt + M[0][3]);
    const float gy = 2.0f * (M[1][0] * Xt + M[1][1] * Yt + M[1][2] * Zt + M[1][3]);
    const float gz = 2.0f * (M[2][0] * Xt + M[2][1] * Yt + M[2][2] * Zt + M[2][3]);
    const float ix = (gx + 1.0f) * 31.5f, iy = (gy + 1.0f) * 31.5f, iz = (gz + 1.0f) * 31.5f;
    const float fx0 = floorf(ix), fy0 = floorf(iy), fz0 = floorf(iz);
    const float fx = ix - fx0, fy = iy - fy0, fz = iz - fz0;
    const int x0 = (int)fx0, y0 = (int)fy0, z0 = (int)fz0;
    const float ax0 = (1.0f - fx) * ((x0 >= 0 && x0 < WV) ? 1.0f : 0.0f);
    const float ax1 = fx * ((x0 + 1 >= 0 && x0 + 1 < WV) ? 1.0f : 0.0f);
    const float ay0 = (1.0f - fy) * ((y0 >= 0 && y0 < HV) ? 1.0f : 0.0f);
    const float ay1 = fy * ((y0 + 1 >= 0 && y0 + 1 < HV) ? 1.0f : 0.0f);
    const float az0 = (1.0f - fz) * ((z0 >= 0 && z0 < DV) ? 1.0f : 0.0f);
    const float az1 = fz * ((z0 + 1 >= 0 && z0 + 1 < DV) ? 1.0f : 0.0f);
    const int xc0 = min(max(x0, 0), WV - 1), xc1 = min(max(x0 + 1, 0), WV - 1);
    const int yc0 = min(max(y0, 0), HV - 1), yc1 = min(max(y0 + 1, 0), HV - 1);
    const int zc0 = min(max(z0, 0), DV - 1), zc1 = min(max(z0 + 1, 0), DV - 1);
    const int o000 = (zc0 * HV + yc0) * WV + xc0, o001 = (zc0 * HV + yc0) * WV + xc1;
    const int o010 = (zc0 * HV + yc1) * WV + xc0, o011 = (zc0 * HV + yc1) * WV + xc1;
    const int o100 = (zc1 * HV + yc0) * WV + xc0, o101 = (zc1 * HV + yc0) * WV + xc1;
    const int o110 = (zc1 * HV + yc1) * WV + xc0, o111 = (zc1 * HV + yc1) * WV + xc1;
    const float* p = vox + (size_t)b * Cn * VOXCH;
    float* op = out + (size_t)b * Cn * SP + sp;
#pragma unroll 8
    for (int cc = 0; cc < Cn; ++cc) {
        const float v000 = p[o000], v001 = p[o001];
        const float v010 = p[o010], v011 = p[o011];
        const float v100 = p[o100], v101 = p[o101];
        const float v110 = p[o110], v111 = p[o111];
        const float q00 = ax0 * v000 + ax1 * v001;
        const float q01 = ax0 * v010 + ax1 * v011;
        const float q10 = ax0 * v100 + ax1 * v101;
        const float q11 = ax0 * v110 + ax1 * v111;
        const float r0 = ay0 * q00 + ay1 * q01;
        const float r1 = ay0 * q10 + ay1 * q11;
        __builtin_nontemporal_store(az0 * r0 + az1 * r1, op);
        p += VOXCH; op += SP;
    }
}

extern "C" void kernel_launch(void* const* d_in, const int* in_sizes, int n_in,
                              void* d_out, int out_size, void* d_ws, size_t ws_size,
                              hipStream_t stream) {
    const float* vox  = (const float*)d_in[0];
    const float* rot  = (const float*)d_in[1];
    const float* tran = (const float*)d_in[2];
    const float* sc   = (const float*)d_in[3];
    const float* det  = (const float*)d_in[4];
    float* out = (float*)d_out;

    if (ws_size >= WS_NEED) {
        float* voxt = (float*)d_ws;
        transpose_cl<<<dim3(Bn * (int)(VOXCH / 64)), dim3(256), 0, stream>>>(vox, voxt);
        sample_cl<<<dim3(NBLK2), dim3(192), 0, stream>>>(voxt, rot, tran, sc, det, out);
    } else {
        persp3d_fallback<<<dim3(NBLOCKS), dim3(256), 0, stream>>>(vox, rot, tran, sc, det, out);
    }
}

// Round 4
// 135.820 us; speedup vs baseline: 4.4878x; 1.4795x over previous
//
#include <hip/hip_runtime.h>

// Perspective3d: voxels [4,32,64,64,64] f32 -> out [4,32,48,96,96] f32.
//
// Round 4: dedup the per-sample coordinate math (was recomputed identically
// by all 32 channel-lanes -> VALUBusy 92%). Phase 1: 96 threads compute one
// sample each, store 8 corner byte-offsets + 8 combined trilinear weights to
// LDS. Phase 2: lane=channel gather reads them broadcast from LDS; per-lane
// work is just 8 adds + 8 coalesced loads + 8 FMAs. Channels-last voxel copy
// (transpose_cl) and LDS output transpose as in round 3.

static constexpr int Bn = 4, Cn = 32, DV = 64, HV = 64, WV = 64;
static constexpr int ZS = 48, XY = 96;
static constexpr int SP = ZS * XY * XY;            // 442368 spatial / batch
static constexpr long long VOXCH = (long long)DV * HV * WV;  // 262144
static constexpr size_t WS_NEED = (size_t)Bn * VOXCH * Cn * 4;  // 134.2 MB

// ---------------- pre-pass: [B,C,DHW] -> [B,DHW,C] ----------------
__global__ __launch_bounds__(256) void transpose_cl(
    const float* __restrict__ vox, float* __restrict__ voxt)
{
    __shared__ float tile[32][65];
    const int nt = (int)(VOXCH / 64);          // 4096 tiles per batch
    const int blk = blockIdx.x;
    const int b  = blk / nt;
    const int v0 = (blk - b * nt) * 64;
    const int t  = threadIdx.x;
    {
        const int c = t >> 3;                  // 0..31
        const int i = (t & 7) * 8;             // 0..56
        const float* src = vox + ((size_t)(b * Cn + c)) * VOXCH + v0 + i;
        const float4 a0 = *(const float4*)src;
        const float4 a1 = *(const float4*)(src + 4);
        tile[c][i + 0] = a0.x; tile[c][i + 1] = a0.y;
        tile[c][i + 2] = a0.z; tile[c][i + 3] = a0.w;
        tile[c][i + 4] = a1.x; tile[c][i + 5] = a1.y;
        tile[c][i + 6] = a1.z; tile[c][i + 7] = a1.w;
    }
    __syncthreads();
    {
        const int v = t >> 2;                  // 0..63
        const int c = (t & 3) * 8;             // 0,8,16,24
        float4 o0, o1;
        o0.x = tile[c + 0][v]; o0.y = tile[c + 1][v];
        o0.z = tile[c + 2][v]; o0.w = tile[c + 3][v];
        o1.x = tile[c + 4][v]; o1.y = tile[c + 5][v];
        o1.z = tile[c + 6][v]; o1.w = tile[c + 7][v];
        float* dst = voxt + ((size_t)b * VOXCH + v0 + v) * Cn + c;
        *(float4*)dst = o0;
        *((float4*)(dst + 4)) = o1;
    }
}

// ---------------- main: phase-split sample kernel ----------------
static constexpr int NBLK2 = Bn * ZS * XY;     // 18432 blocks (one (b,z,h) row)
static constexpr int CH2   = NBLK2 / 8;        // 2304 per XCD

__global__ __launch_bounds__(192) void sample_cl(
    const float* __restrict__ voxt,
    const float* __restrict__ rot,
    const float* __restrict__ tran,
    const float* __restrict__ sc,
    const float* __restrict__ det,
    float* __restrict__ out)
{
    __shared__ __align__(16) int   soff[96][8];   // corner byte offsets
    __shared__ __align__(16) float swt[96][8];    // combined trilinear weights
    __shared__ float tr[3][32][33];               // output transpose tiles

    // bijective XCD-chunk swizzle (18432 % 8 == 0)
    const int logical = (blockIdx.x % 8) * CH2 + blockIdx.x / 8;
    const int b   = logical / (ZS * XY);
    const int rem = logical - b * (ZS * XY);
    const int z   = rem / XY;
    const int h   = rem - z * XY;

    const int t = threadIdx.x;

    // ---- phase 1: one thread per sample computes offsets + weights ----
    if (t < XY) {
        const float* R  = rot  + b * 16;
        const float* T  = tran + b * 3;
        const float* S  = sc   + b * 3;
        const float* DT = det  + b * 2;
        const float t0 = T[0], t1 = T[1], t2 = T[2];

        float M[3][4];
#pragma unroll
        for (int i2 = 0; i2 < 3; ++i2) {
            const float inv = 1.0f / S[i2];
            const float m0 = R[0 * 4 + i2], m1 = R[1 * 4 + i2], m2 = R[2 * 4 + i2];
            M[i2][0] = inv * m0;
            M[i2][1] = inv * m1;
            M[i2][2] = inv * m2;
            M[i2][3] = -inv * (m0 * t0 + m1 * t1 + m2 * t2);
        }

        const float STEP = 96.0f / 95.0f;
        const float Zt = -0.5f + z * (1.0f / 47.0f) + t2;
        const float Xt = (t * STEP - 48.0f + DT[0]) * Zt * 0.01f;
        const float Yt = (h * STEP - 48.0f + DT[1]) * Zt * 0.01f;

        const float gx = 2.0f * (M[0][0] * Xt + M[0][1] * Yt + M[0][2] * Zt + M[0][3]);
        const float gy = 2.0f * (M[1][0] * Xt + M[1][1] * Yt + M[1][2] * Zt + M[1][3]);
        const float gz = 2.0f * (M[2][0] * Xt + M[2][1] * Yt + M[2][2] * Zt + M[2][3]);

        const float ix = (gx + 1.0f) * 31.5f;
        const float iy = (gy + 1.0f) * 31.5f;
        const float iz = (gz + 1.0f) * 31.5f;

        const float fxf = floorf(ix), fyf = floorf(iy), fzf = floorf(iz);
        const float fx = ix - fxf, fy = iy - fyf, fz = iz - fzf;
        const int x0 = (int)fxf, y0 = (int)fyf, z0 = (int)fzf;

        const float ax0 = (1.0f - fx) * ((x0 >= 0     && x0 < WV)     ? 1.0f : 0.0f);
        const float ax1 = fx          * ((x0 + 1 >= 0 && x0 + 1 < WV) ? 1.0f : 0.0f);
        const float ay0 = (1.0f - fy) * ((y0 >= 0     && y0 < HV)     ? 1.0f : 0.0f);
        const float ay1 = fy          * ((y0 + 1 >= 0 && y0 + 1 < HV) ? 1.0f : 0.0f);
        const float az0 = (1.0f - fz) * ((z0 >= 0     && z0 < DV)     ? 1.0f : 0.0f);
        const float az1 = fz          * ((z0 + 1 >= 0 && z0 + 1 < DV) ? 1.0f : 0.0f);

        const int xc0 = min(max(x0, 0), WV - 1), xc1 = min(max(x0 + 1, 0), WV - 1);
        const int yc0 = min(max(y0, 0), HV - 1), yc1 = min(max(y0 + 1, 0), HV - 1);
        const int zc0 = min(max(z0, 0), DV - 1), zc1 = min(max(z0 + 1, 0), DV - 1);

        const int r00 = (zc0 * HV + yc0) * WV;
        const int r01 = (zc0 * HV + yc1) * WV;
        const int r10 = (zc1 * HV + yc0) * WV;
        const int r11 = (zc1 * HV + yc1) * WV;

        // byte offsets into channels-last volume (elem stride = Cn*4 = 128 B)
        soff[t][0] = (r00 + xc0) << 7;
        soff[t][1] = (r00 + xc1) << 7;
        soff[t][2] = (r01 + xc0) << 7;
        soff[t][3] = (r01 + xc1) << 7;
        soff[t][4] = (r10 + xc0) << 7;
        soff[t][5] = (r10 + xc1) << 7;
        soff[t][6] = (r11 + xc0) << 7;
        soff[t][7] = (r11 + xc1) << 7;

        const float wz0y0 = az0 * ay0, wz0y1 = az0 * ay1;
        const float wz1y0 = az1 * ay0, wz1y1 = az1 * ay1;
        swt[t][0] = wz0y0 * ax0;
        swt[t][1] = wz0y0 * ax1;
        swt[t][2] = wz0y1 * ax0;
        swt[t][3] = wz0y1 * ax1;
        swt[t][4] = wz1y0 * ax0;
        swt[t][5] = wz1y0 * ax1;
        swt[t][6] = wz1y1 * ax0;
        swt[t][7] = wz1y1 * ax1;
    }
    __syncthreads();

    // ---- phase 2: gather. lane = channel, half-wave = one sample ----
    const int wave = t >> 6;                   // 0..2 -> w-tile of 32
    const int lane = t & 63;
    const int p    = lane >> 5;                // sample parity within pair
    const int c    = lane & 31;                // channel owned by this lane
    const int w0   = wave * 32;

    const char* vb = (const char*)(voxt + (size_t)b * VOXCH * Cn);
    const int c4 = c * 4;

#pragma unroll 4
    for (int i = 0; i < 16; ++i) {
        const int s = w0 + 2 * i + p;
        const int4   o0 = *(const int4*)(&soff[s][0]);
        const int4   o1 = *(const int4*)(&soff[s][4]);
        const float4 wa = *(const float4*)(&swt[s][0]);
        const float4 wb = *(const float4*)(&swt[s][4]);

        const float v000 = *(const float*)(vb + (o0.x + c4));
        const float v001 = *(const float*)(vb + (o0.y + c4));
        const float v010 = *(const float*)(vb + (o0.z + c4));
        const float v011 = *(const float*)(vb + (o0.w + c4));
        const float v100 = *(const float*)(vb + (o1.x + c4));
        const float v101 = *(const float*)(vb + (o1.y + c4));
        const float v110 = *(const float*)(vb + (o1.z + c4));
        const float v111 = *(const float*)(vb + (o1.w + c4));

        float acc = wa.x * v000;
        acc = fmaf(wa.y, v001, acc);
        acc = fmaf(wa.z, v010, acc);
        acc = fmaf(wa.w, v011, acc);
        acc = fmaf(wb.x, v100, acc);
        acc = fmaf(wb.y, v101, acc);
        acc = fmaf(wb.z, v110, acc);
        acc = fmaf(wb.w, v111, acc);

        tr[wave][2 * i + p][c] = acc;
    }

    __syncthreads();

    // ---- store: lanes -> consecutive w, coalesced rows per channel ----
    const size_t obase = (size_t)b * Cn * SP + (size_t)(z * XY + h) * XY + w0;
    const int wl = lane & 31;
#pragma unroll
    for (int c2 = 0; c2 < 16; ++c2) {
        const int cc = 2 * c2 + p;
        __builtin_nontemporal_store(tr[wave][wl][cc],
                                    out + obase + (size_t)cc * SP + wl);
    }
}

// ---------------- fallback (round-2 kernel) if ws too small ----------------
static constexpr int TW = 32, TH = 4, TZ = 2;
static constexpr int NBW = XY / TW, NBH = XY / TH, NBZ = ZS / TZ;
static constexpr int BLOCKS_PER_B = NBW * NBH * NBZ;
static constexpr int NBLOCKS = Bn * BLOCKS_PER_B;
static constexpr int CHUNK = NBLOCKS / 8;

__global__ __launch_bounds__(256) void persp3d_fallback(
    const float* __restrict__ vox, const float* __restrict__ rot,
    const float* __restrict__ tran, const float* __restrict__ sc,
    const float* __restrict__ det, float* __restrict__ out)
{
    const int xcd = blockIdx.x % 8;
    const int logical = xcd * CHUNK + blockIdx.x / 8;
    const int b = logical / BLOCKS_PER_B;
    int rem = logical - b * BLOCKS_PER_B;
    const int bz = rem / (NBH * NBW);
    rem -= bz * (NBH * NBW);
    const int bh = rem / NBW;
    const int bw = rem - bh * NBW;
    const int t = threadIdx.x;
    const int w = bw * TW + (t & (TW - 1));
    const int h = bh * TH + ((t >> 5) & (TH - 1));
    const int z = bz * TZ + (t >> 7);
    const int sp = (z * XY + h) * XY + w;

    const float* R = rot + b * 16;
    const float* T = tran + b * 3;
    const float* S = sc + b * 3;
    const float* DT = det + b * 2;
    const float t0 = T[0], t1 = T[1], t2 = T[2];
    float M[3][4];
#pragma unroll
    for (int i = 0; i < 3; ++i) {
        const float inv = 1.0f / S[i];
        const float m0 = R[0 * 4 + i], m1 = R[1 * 4 + i], m2 = R[2 * 4 + i];
        M[i][0] = inv * m0; M[i][1] = inv * m1; M[i][2] = inv * m2;
        M[i][3] = -inv * (m0 * t0 + m1 * t1 + m2 * t2);
    }
    const float STEP = 96.0f / 95.0f;
    const float Zt = -0.5f + z * (1.0f / 47.0f) + t2;
    const float Xt = (w * STEP - 48.0f + DT[0]) * Zt * 0.01f;
    const float Yt = (h * STEP - 48.0f + DT[1]) * Zt * 0.01f;
    const float gx = 2.0f * (M[0][0] * Xt + M[0][1] * Yt + M[0][2] * Zt + M[0][3]);
    const float gy = 2.0f * (M[1][0] * Xt + M[1][1] * Yt + M[1][2] * Zt + M[1][3]);
    const float gz = 2.0f * (M[2][0] * Xt + M[2][1] * Yt + M[2][2] * Zt + M[2][3]);
    const float ix = (gx + 1.0f) * 31.5f, iy = (gy + 1.0f) * 31.5f, iz = (gz + 1.0f) * 31.5f;
    const float fx0 = floorf(ix), fy0 = floorf(iy), fz0 = floorf(iz);
    const float fx = ix - fx0, fy = iy - fy0, fz = iz - fz0;
    const int x0 = (int)fx0, y0 = (int)fy0, z0 = (int)fz0;
    const float ax0 = (1.0f - fx) * ((x0 >= 0 && x0 < WV) ? 1.0f : 0.0f);
    const float ax1 = fx * ((x0 + 1 >= 0 && x0 + 1 < WV) ? 1.0f : 0.0f);
    const float ay0 = (1.0f - fy) * ((y0 >= 0 && y0 < HV) ? 1.0f : 0.0f);
    const float ay1 = fy * ((y0 + 1 >= 0 && y0 + 1 < HV) ? 1.0f : 0.0f);
    const float az0 = (1.0f - fz) * ((z0 >= 0 && z0 < DV) ? 1.0f : 0.0f);
    const float az1 = fz * ((z0 + 1 >= 0 && z0 + 1 < DV) ? 1.0f : 0.0f);
    const int xc0 = min(max(x0, 0), WV - 1), xc1 = min(max(x0 + 1, 0), WV - 1);
    const int yc0 = min(max(y0, 0), HV - 1), yc1 = min(max(y0 + 1, 0), HV - 1);
    const int zc0 = min(max(z0, 0), DV - 1), zc1 = min(max(z0 + 1, 0), DV - 1);
    const int o000 = (zc0 * HV + yc0) * WV + xc0, o001 = (zc0 * HV + yc0) * WV + xc1;
    const int o010 = (zc0 * HV + yc1) * WV + xc0, o011 = (zc0 * HV + yc1) * WV + xc1;
    const int o100 = (zc1 * HV + yc0) * WV + xc0, o101 = (zc1 * HV + yc0) * WV + xc1;
    const int o110 = (zc1 * HV + yc1) * WV + xc0, o111 = (zc1 * HV + yc1) * WV + xc1;
    const float* p = vox + (size_t)b * Cn * VOXCH;
    float* op = out + (size_t)b * Cn * SP + sp;
#pragma unroll 8
    for (int cc = 0; cc < Cn; ++cc) {
        const float v000 = p[o000], v001 = p[o001];
        const float v010 = p[o010], v011 = p[o011];
        const float v100 = p[o100], v101 = p[o101];
        const float v110 = p[o110], v111 = p[o111];
        const float q00 = ax0 * v000 + ax1 * v001;
        const float q01 = ax0 * v010 + ax1 * v011;
        const float q10 = ax0 * v100 + ax1 * v101;
        const float q11 = ax0 * v110 + ax1 * v111;
        const float r0 = ay0 * q00 + ay1 * q01;
        const float r1 = ay0 * q10 + ay1 * q11;
        __builtin_nontemporal_store(az0 * r0 + az1 * r1, op);
        p += VOXCH; op += SP;
    }
}

extern "C" void kernel_launch(void* const* d_in, const int* in_sizes, int n_in,
                              void* d_out, int out_size, void* d_ws, size_t ws_size,
                              hipStream_t stream) {
    const float* vox  = (const float*)d_in[0];
    const float* rot  = (const float*)d_in[1];
    const float* tran = (const float*)d_in[2];
    const float* sc   = (const float*)d_in[3];
    const float* det  = (const float*)d_in[4];
    float* out = (float*)d_out;

    if (ws_size >= WS_NEED) {
        float* voxt = (float*)d_ws;
        transpose_cl<<<dim3(Bn * (int)(VOXCH / 64)), dim3(256), 0, stream>>>(vox, voxt);
        sample_cl<<<dim3(NBLK2), dim3(192), 0, stream>>>(voxt, rot, tran, sc, det, out);
    } else {
        persp3d_fallback<<<dim3(NBLOCKS), dim3(256), 0, stream>>>(vox, rot, tran, sc, det, out);
    }
}

// Round 5
// 90.295 us; speedup vs baseline: 6.7504x; 1.5042x over previous
//
#include <hip/hip_runtime.h>
#include <hip/hip_fp16.h>

// Perspective3d: voxels [4,32,64,64,64] f32 -> out [4,32,48,96,96] f32.
//
// Round 5: halve gather line traffic with fp16 channels-last voxels.
// transpose_cl: [B,C,DHW] f32 -> [B,DHW,C] f16 (64 B/voxel). sample_cl:
// phase-split (96 threads compute per-sample corner offsets + combined
// weights into LDS), then 16 lanes per sample gather 2 channels each via
// one dword (__half2) load -> cvt -> 2 FMA. LDS transpose for coalesced
// output stores. XCD-chunk swizzle throughout.

static constexpr int Bn = 4, Cn = 32, DV = 64, HV = 64, WV = 64;
static constexpr int ZS = 48, XY = 96;
static constexpr int SP = ZS * XY * XY;            // 442368 spatial / batch
static constexpr long long VOXCH = (long long)DV * HV * WV;  // 262144
static constexpr size_t WS_NEED = (size_t)Bn * VOXCH * Cn * sizeof(__half); // 67 MB

static __device__ __forceinline__ unsigned pk2h(float a, float b) {
    __half2 h2;
    h2.x = __float2half(a);
    h2.y = __float2half(b);
    return *reinterpret_cast<unsigned*>(&h2);
}

// ---------------- pre-pass: [B,C,DHW] f32 -> [B,DHW,C] f16 ----------------
__global__ __launch_bounds__(256) void transpose_cl(
    const float* __restrict__ vox, __half* __restrict__ voxt)
{
    __shared__ float tile[32][65];
    const int nt = (int)(VOXCH / 64);          // 4096 tiles per batch
    const int blk = blockIdx.x;
    const int b  = blk / nt;
    const int v0 = (blk - b * nt) * 64;
    const int t  = threadIdx.x;
    {
        const int c = t >> 3;                  // 0..31
        const int i = (t & 7) * 8;             // 0..56
        const float* src = vox + ((size_t)(b * Cn + c)) * VOXCH + v0 + i;
        const float4 a0 = *(const float4*)src;
        const float4 a1 = *(const float4*)(src + 4);
        tile[c][i + 0] = a0.x; tile[c][i + 1] = a0.y;
        tile[c][i + 2] = a0.z; tile[c][i + 3] = a0.w;
        tile[c][i + 4] = a1.x; tile[c][i + 5] = a1.y;
        tile[c][i + 6] = a1.z; tile[c][i + 7] = a1.w;
    }
    __syncthreads();
    {
        const int v  = t >> 2;                 // 0..63
        const int c8 = (t & 3) * 8;            // 0,8,16,24
        const unsigned p0 = pk2h(tile[c8 + 0][v], tile[c8 + 1][v]);
        const unsigned p1 = pk2h(tile[c8 + 2][v], tile[c8 + 3][v]);
        const unsigned p2 = pk2h(tile[c8 + 4][v], tile[c8 + 5][v]);
        const unsigned p3 = pk2h(tile[c8 + 6][v], tile[c8 + 7][v]);
        __half* dst = voxt + ((size_t)b * VOXCH + v0 + v) * Cn + c8;
        *(uint4*)dst = make_uint4(p0, p1, p2, p3);   // 16 B aligned (c8*2B in {0,16,32,48})
    }
}

// ---------------- main: phase-split fp16 sample kernel ----------------
static constexpr int NBLK2 = Bn * ZS * XY;     // 18432 blocks (one (b,z,h) row)
static constexpr int CH2   = NBLK2 / 8;        // 2304 per XCD

__global__ __launch_bounds__(192) void sample_cl(
    const __half* __restrict__ voxt,
    const float* __restrict__ rot,
    const float* __restrict__ tran,
    const float* __restrict__ sc,
    const float* __restrict__ det,
    float* __restrict__ out)
{
    __shared__ __align__(16) int   soff[96][8];   // corner byte offsets (64B/voxel)
    __shared__ __align__(16) float swt[96][8];    // combined trilinear weights
    __shared__ float tr[3][32][34];               // per-wave output transpose tile

    // bijective XCD-chunk swizzle (18432 % 8 == 0)
    const int logical = (blockIdx.x % 8) * CH2 + blockIdx.x / 8;
    const int b   = logical / (ZS * XY);
    const int rem = logical - b * (ZS * XY);
    const int z   = rem / XY;
    const int h   = rem - z * XY;

    const int t = threadIdx.x;

    // ---- phase 1: one thread per sample computes offsets + weights ----
    if (t < XY) {
        const float* R  = rot  + b * 16;
        const float* T  = tran + b * 3;
        const float* S  = sc   + b * 3;
        const float* DT = det  + b * 2;
        const float t0 = T[0], t1 = T[1], t2 = T[2];

        float M[3][4];
#pragma unroll
        for (int i2 = 0; i2 < 3; ++i2) {
            const float inv = 1.0f / S[i2];
            const float m0 = R[0 * 4 + i2], m1 = R[1 * 4 + i2], m2 = R[2 * 4 + i2];
            M[i2][0] = inv * m0;
            M[i2][1] = inv * m1;
            M[i2][2] = inv * m2;
            M[i2][3] = -inv * (m0 * t0 + m1 * t1 + m2 * t2);
        }

        const float STEP = 96.0f / 95.0f;
        const float Zt = -0.5f + z * (1.0f / 47.0f) + t2;
        const float Xt = (t * STEP - 48.0f + DT[0]) * Zt * 0.01f;
        const float Yt = (h * STEP - 48.0f + DT[1]) * Zt * 0.01f;

        const float gx = 2.0f * (M[0][0] * Xt + M[0][1] * Yt + M[0][2] * Zt + M[0][3]);
        const float gy = 2.0f * (M[1][0] * Xt + M[1][1] * Yt + M[1][2] * Zt + M[1][3]);
        const float gz = 2.0f * (M[2][0] * Xt + M[2][1] * Yt + M[2][2] * Zt + M[2][3]);

        const float ix = (gx + 1.0f) * 31.5f;
        const float iy = (gy + 1.0f) * 31.5f;
        const float iz = (gz + 1.0f) * 31.5f;

        const float fxf = floorf(ix), fyf = floorf(iy), fzf = floorf(iz);
        const float fx = ix - fxf, fy = iy - fyf, fz = iz - fzf;
        const int x0 = (int)fxf, y0 = (int)fyf, z0 = (int)fzf;

        const float ax0 = (1.0f - fx) * ((x0 >= 0     && x0 < WV)     ? 1.0f : 0.0f);
        const float ax1 = fx          * ((x0 + 1 >= 0 && x0 + 1 < WV) ? 1.0f : 0.0f);
        const float ay0 = (1.0f - fy) * ((y0 >= 0     && y0 < HV)     ? 1.0f : 0.0f);
        const float ay1 = fy          * ((y0 + 1 >= 0 && y0 + 1 < HV) ? 1.0f : 0.0f);
        const float az0 = (1.0f - fz) * ((z0 >= 0     && z0 < DV)     ? 1.0f : 0.0f);
        const float az1 = fz          * ((z0 + 1 >= 0 && z0 + 1 < DV) ? 1.0f : 0.0f);

        const int xc0 = min(max(x0, 0), WV - 1), xc1 = min(max(x0 + 1, 0), WV - 1);
        const int yc0 = min(max(y0, 0), HV - 1), yc1 = min(max(y0 + 1, 0), HV - 1);
        const int zc0 = min(max(z0, 0), DV - 1), zc1 = min(max(z0 + 1, 0), DV - 1);

        const int r00 = (zc0 * HV + yc0) * WV;
        const int r01 = (zc0 * HV + yc1) * WV;
        const int r10 = (zc1 * HV + yc0) * WV;
        const int r11 = (zc1 * HV + yc1) * WV;

        // byte offsets into f16 channels-last volume (voxel stride = 64 B)
        soff[t][0] = (r00 + xc0) << 6;
        soff[t][1] = (r00 + xc1) << 6;
        soff[t][2] = (r01 + xc0) << 6;
        soff[t][3] = (r01 + xc1) << 6;
        soff[t][4] = (r10 + xc0) << 6;
        soff[t][5] = (r10 + xc1) << 6;
        soff[t][6] = (r11 + xc0) << 6;
        soff[t][7] = (r11 + xc1) << 6;

        const float wz0y0 = az0 * ay0, wz0y1 = az0 * ay1;
        const float wz1y0 = az1 * ay0, wz1y1 = az1 * ay1;
        swt[t][0] = wz0y0 * ax0;
        swt[t][1] = wz0y0 * ax1;
        swt[t][2] = wz0y1 * ax0;
        swt[t][3] = wz0y1 * ax1;
        swt[t][4] = wz1y0 * ax0;
        swt[t][5] = wz1y0 * ax1;
        swt[t][6] = wz1y1 * ax0;
        swt[t][7] = wz1y1 * ax1;
    }
    __syncthreads();

    // ---- phase 2: gather. 16 lanes per sample, 2 channels per lane ----
    const int wave = t >> 6;                   // 0..2 -> w-tile of 32
    const int lane = t & 63;
    const int sg   = lane >> 4;                // sample-in-quad 0..3
    const int li   = lane & 15;                // channel-pair index
    const int w0   = wave * 32;
    const int lb   = li * 4;                   // byte offset within 64B corner

    const char* vb = (const char*)voxt + (size_t)b * VOXCH * (Cn * 2);

#pragma unroll
    for (int i = 0; i < 8; ++i) {
        const int s  = w0 + 4 * i + sg;
        const int sl = s & 31;
        const int4   o0 = *(const int4*)(&soff[s][0]);
        const int4   o1 = *(const int4*)(&soff[s][4]);
        const float4 wa = *(const float4*)(&swt[s][0]);
        const float4 wb = *(const float4*)(&swt[s][4]);

        const float2 f0 = __half22float2(*(const __half2*)(vb + (o0.x + lb)));
        const float2 f1 = __half22float2(*(const __half2*)(vb + (o0.y + lb)));
        const float2 f2 = __half22float2(*(const __half2*)(vb + (o0.z + lb)));
        const float2 f3 = __half22float2(*(const __half2*)(vb + (o0.w + lb)));
        const float2 f4 = __half22float2(*(const __half2*)(vb + (o1.x + lb)));
        const float2 f5 = __half22float2(*(const __half2*)(vb + (o1.y + lb)));
        const float2 f6 = __half22float2(*(const __half2*)(vb + (o1.z + lb)));
        const float2 f7 = __half22float2(*(const __half2*)(vb + (o1.w + lb)));

        float acc0 = wa.x * f0.x;
        float acc1 = wa.x * f0.y;
        acc0 = fmaf(wa.y, f1.x, acc0); acc1 = fmaf(wa.y, f1.y, acc1);
        acc0 = fmaf(wa.z, f2.x, acc0); acc1 = fmaf(wa.z, f2.y, acc1);
        acc0 = fmaf(wa.w, f3.x, acc0); acc1 = fmaf(wa.w, f3.y, acc1);
        acc0 = fmaf(wb.x, f4.x, acc0); acc1 = fmaf(wb.x, f4.y, acc1);
        acc0 = fmaf(wb.y, f5.x, acc0); acc1 = fmaf(wb.y, f5.y, acc1);
        acc0 = fmaf(wb.z, f6.x, acc0); acc1 = fmaf(wb.z, f6.y, acc1);
        acc0 = fmaf(wb.w, f7.x, acc0); acc1 = fmaf(wb.w, f7.y, acc1);

        *(float2*)(&tr[wave][sl][li * 2]) = make_float2(acc0, acc1);
    }

    __syncthreads();

    // ---- store: lanes -> consecutive w, coalesced rows per channel ----
    const size_t obase = (size_t)b * Cn * SP + (size_t)(z * XY + h) * XY + w0;
    const int p  = lane >> 5;
    const int wl = lane & 31;
#pragma unroll
    for (int c2 = 0; c2 < 16; ++c2) {
        const int cc = 2 * c2 + p;
        __builtin_nontemporal_store(tr[wave][wl][cc],
                                    out + obase + (size_t)cc * SP + wl);
    }
}

// ---------------- fallback (round-2 kernel) if ws too small ----------------
static constexpr int TW = 32, TH = 4, TZ = 2;
static constexpr int NBW = XY / TW, NBH = XY / TH, NBZ = ZS / TZ;
static constexpr int BLOCKS_PER_B = NBW * NBH * NBZ;
static constexpr int NBLOCKS = Bn * BLOCKS_PER_B;
static constexpr int CHUNK = NBLOCKS / 8;

__global__ __launch_bounds__(256) void persp3d_fallback(
    const float* __restrict__ vox, const float* __restrict__ rot,
    const float* __restrict__ tran, const float* __restrict__ sc,
    const float* __restrict__ det, float* __restrict__ out)
{
    const int xcd = blockIdx.x % 8;
    const int logical = xcd * CHUNK + blockIdx.x / 8;
    const int b = logical / BLOCKS_PER_B;
    int rem = logical - b * BLOCKS_PER_B;
    const int bz = rem / (NBH * NBW);
    rem -= bz * (NBH * NBW);
    const int bh = rem / NBW;
    const int bw = rem - bh * NBW;
    const int t = threadIdx.x;
    const int w = bw * TW + (t & (TW - 1));
    const int h = bh * TH + ((t >> 5) & (TH - 1));
    const int z = bz * TZ + (t >> 7);
    const int sp = (z * XY + h) * XY + w;

    const float* R = rot + b * 16;
    const float* T = tran + b * 3;
    const float* S = sc + b * 3;
    const float* DT = det + b * 2;
    const float t0 = T[0], t1 = T[1], t2 = T[2];
    float M[3][4];
#pragma unroll
    for (int i = 0; i < 3; ++i) {
        const float inv = 1.0f / S[i];
        const float m0 = R[0 * 4 + i], m1 = R[1 * 4 + i], m2 = R[2 * 4 + i];
        M[i][0] = inv * m0; M[i][1] = inv * m1; M[i][2] = inv * m2;
        M[i][3] = -inv * (m0 * t0 + m1 * t1 + m2 * t2);
    }
    const float STEP = 96.0f / 95.0f;
    const float Zt = -0.5f + z * (1.0f / 47.0f) + t2;
    const float Xt = (w * STEP - 48.0f + DT[0]) * Zt * 0.01f;
    const float Yt = (h * STEP - 48.0f + DT[1]) * Zt * 0.01f;
    const float gx = 2.0f * (M[0][0] * Xt + M[0][1] * Yt + M[0][2] * Zt + M[0][3]);
    const float gy = 2.0f * (M[1][0] * Xt + M[1][1] * Yt + M[1][2] * Zt + M[1][3]);
    const float gz = 2.0f * (M[2][0] * Xt + M[2][1] * Yt + M[2][2] * Zt + M[2][3]);
    const float ix = (gx + 1.0f) * 31.5f, iy = (gy + 1.0f) * 31.5f, iz = (gz + 1.0f) * 31.5f;
    const float fx0 = floorf(ix), fy0 = floorf(iy), fz0 = floorf(iz);
    const float fx = ix - fx0, fy = iy - fy0, fz = iz - fz0;
    const int x0 = (int)fx0, y0 = (int)fy0, z0 = (int)fz0;
    const float ax0 = (1.0f - fx) * ((x0 >= 0 && x0 < WV) ? 1.0f : 0.0f);
    const float ax1 = fx * ((x0 + 1 >= 0 && x0 + 1 < WV) ? 1.0f : 0.0f);
    const float ay0 = (1.0f - fy) * ((y0 >= 0 && y0 < HV) ? 1.0f : 0.0f);
    const float ay1 = fy * ((y0 + 1 >= 0 && y0 + 1 < HV) ? 1.0f : 0.0f);
    const float az0 = (1.0f - fz) * ((z0 >= 0 && z0 < DV) ? 1.0f : 0.0f);
    const float az1 = fz * ((z0 + 1 >= 0 && z0 + 1 < DV) ? 1.0f : 0.0f);
    const int xc0 = min(max(x0, 0), WV - 1), xc1 = min(max(x0 + 1, 0), WV - 1);
    const int yc0 = min(max(y0, 0), HV - 1), yc1 = min(max(y0 + 1, 0), HV - 1);
    const int zc0 = min(max(z0, 0), DV - 1), zc1 = min(max(z0 + 1, 0), DV - 1);
    const int o000 = (zc0 * HV + yc0) * WV + xc0, o001 = (zc0 * HV + yc0) * WV + xc1;
    const int o010 = (zc0 * HV + yc1) * WV + xc0, o011 = (zc0 * HV + yc1) * WV + xc1;
    const int o100 = (zc1 * HV + yc0) * WV + xc0, o101 = (zc1 * HV + yc0) * WV + xc1;
    const int o110 = (zc1 * HV + yc1) * WV + xc0, o111 = (zc1 * HV + yc1) * WV + xc1;
    const float* p = vox + (size_t)b * Cn * VOXCH;
    float* op = out + (size_t)b * Cn * SP + sp;
#pragma unroll 8
    for (int cc = 0; cc < Cn; ++cc) {
        const float v000 = p[o000], v001 = p[o001];
        const float v010 = p[o010], v011 = p[o011];
        const float v100 = p[o100], v101 = p[o101];
        const float v110 = p[o110], v111 = p[o111];
        const float q00 = ax0 * v000 + ax1 * v001;
        const float q01 = ax0 * v010 + ax1 * v011;
        const float q10 = ax0 * v100 + ax1 * v101;
        const float q11 = ax0 * v110 + ax1 * v111;
        const float r0 = ay0 * q00 + ay1 * q01;
        const float r1 = ay0 * q10 + ay1 * q11;
        __builtin_nontemporal_store(az0 * r0 + az1 * r1, op);
        p += VOXCH; op += SP;
    }
}

extern "C" void kernel_launch(void* const* d_in, const int* in_sizes, int n_in,
                              void* d_out, int out_size, void* d_ws, size_t ws_size,
                              hipStream_t stream) {
    const float* vox  = (const float*)d_in[0];
    const float* rot  = (const float*)d_in[1];
    const float* tran = (const float*)d_in[2];
    const float* sc   = (const float*)d_in[3];
    const float* det  = (const float*)d_in[4];
    float* out = (float*)d_out;

    if (ws_size >= WS_NEED) {
        __half* voxt = (__half*)d_ws;
        transpose_cl<<<dim3(Bn * (int)(VOXCH / 64)), dim3(256), 0, stream>>>(vox, voxt);
        sample_cl<<<dim3(NBLK2), dim3(192), 0, stream>>>(voxt, rot, tran, sc, det, out);
    } else {
        persp3d_fallback<<<dim3(NBLOCKS), dim3(256), 0, stream>>>(vox, rot, tran, sc, det, out);
    }
}